// Round 4
// baseline (220.585 us; speedup 1.0000x reference)
//
#include <hip/hip_runtime.h>
#include <hip/hip_bf16.h>

typedef __bf16 bf16;
typedef __attribute__((ext_vector_type(8))) __bf16 bf16x8;
typedef __attribute__((ext_vector_type(4))) __bf16 bf16x4;
typedef __attribute__((ext_vector_type(16))) float f32x16;

#define N_ROWS 16384
#define DIM 256
#define NJC 512           /* 32-col tiles */
#define NBLKS 1024        /* 4 blocks/CU x 256 CU, one resident round */
#define NTILES 33024      /* sum_{it=0}^{127} (512-4it) */
#define SQK1 4.53981608f  /* sqrt(1/(0.07*ln2)): A pre-scaled so e^{z} = 2^{dot'} */
#define LN2F 0.69314718056f

#define WS_T_OFF (N_ROWS * DIM * 2)
#define WS_D_OFF (WS_T_OFF + N_ROWS * 4)

#define GLOAD_LDS(g, l)                                        \
    __builtin_amdgcn_global_load_lds(                          \
        (const __attribute__((address_space(1))) void*)(g),    \
        (__attribute__((address_space(3))) void*)(l), 16, 0, 0)

// Kernel 1: L2-normalize rows, scale by SQK1, emit bf16 A' to ws. Zeros T[]
// and d_out. Dg[row] = s2' = sum(bf16(SQK1*a)^2) = the MFMA diagonal, so the
// diagonal's bf16 rounding error cancels: loss_i = ln2*(log2(T'_i) - s2'_i).
__global__ void __launch_bounds__(256) normalize_kernel(const float* __restrict__ in,
                                                        bf16* __restrict__ out,
                                                        float* __restrict__ Tg,
                                                        float* __restrict__ Dg,
                                                        float* __restrict__ loss_out) {
    if (blockIdx.x == 0 && threadIdx.x == 0) loss_out[0] = 0.0f;
    if (blockIdx.x < 64) Tg[blockIdx.x * 256 + threadIdx.x] = 0.0f;

    const int row  = blockIdx.x * 4 + (threadIdx.x >> 6);
    const int lane = threadIdx.x & 63;
    const float4* rp = (const float4*)(in + (size_t)row * DIM);
    float4 v = rp[lane];
    float ss = v.x * v.x + v.y * v.y + v.z * v.z + v.w * v.w;
#pragma unroll
    for (int m = 1; m < 64; m <<= 1) ss += __shfl_xor(ss, m, 64);
    float inv = SQK1 / fmaxf(sqrtf(ss), 1e-12f);
    bf16x4 o;
    o[0] = (bf16)(v.x * inv);
    o[1] = (bf16)(v.y * inv);
    o[2] = (bf16)(v.z * inv);
    o[3] = (bf16)(v.w * inv);
    *(bf16x4*)(out + (size_t)row * DIM + lane * 4) = o;

    float f0 = (float)o[0], f1 = (float)o[1], f2 = (float)o[2], f3 = (float)o[3];
    float s2 = f0 * f0 + f1 * f1 + f2 * f2 + f3 * f3;
#pragma unroll
    for (int m = 1; m < 64; m <<= 1) s2 += __shfl_xor(s2, m, 64);
    if (lane == 0) Dg[row] = s2;
}

// Tree-reduce 16 floats across the 32 `lo` lanes; every lane ends with the
// full sum for register index r = (lo>>1)&15. (Correctness-proven R4-R10.)
#define TREE16(R, out)                                                     \
    do {                                                                   \
        float w8[8], w4[4], w2[2], w1, g_;                                 \
        _Pragma("unroll") for (int i_ = 0; i_ < 8; ++i_) {                 \
            g_ = (lo & 16) ? R[i_] : R[i_ + 8];                            \
            w8[i_] = ((lo & 16) ? R[i_ + 8] : R[i_]) + __shfl_xor(g_, 16); \
        }                                                                  \
        _Pragma("unroll") for (int i_ = 0; i_ < 4; ++i_) {                 \
            g_ = (lo & 8) ? w8[i_] : w8[i_ + 4];                           \
            w4[i_] = ((lo & 8) ? w8[i_ + 4] : w8[i_]) + __shfl_xor(g_, 8); \
        }                                                                  \
        _Pragma("unroll") for (int i_ = 0; i_ < 2; ++i_) {                 \
            g_ = (lo & 4) ? w4[i_] : w4[i_ + 2];                           \
            w2[i_] = ((lo & 4) ? w4[i_ + 2] : w4[i_]) + __shfl_xor(g_, 4); \
        }                                                                  \
        g_ = (lo & 2) ? w2[0] : w2[1];                                     \
        w1 = ((lo & 2) ? w2[1] : w2[0]) + __shfl_xor(g_, 2);               \
        out = w1 + __shfl_xor(w1, 1);                                      \
    } while (0)

// Kernel 2: symmetric A'A'^T + softmax denominator.
// R13 -> R14: HALVE THE LDS READ PER OUTPUT. R13's counters: MfmaUtil 29%
// (= exact arithmetic floor 66k cy/CU), LDS pipe ~65% busy (64KB read/tile
// from 4 waves each re-reading the whole 16KB B-tile + 33k cy/CU conflicts)
// — LDS was the dominant pipe, not scheduling. Now: 2-wave blocks (128 thr),
// each wave owns TWO 32-row A-panels (af0/af1, rows w*64 and w*64+32) and
// accumulates two independent MFMA chains (c0a,c0b) sharing every b_
// fragment -> 16B -> 8B of LDS read per output element, conflicts ~halve,
// MFMA-per-sync doubles, and the two chains halve exposed MFMA latency.
// VGPR ~220 -> 2 waves/SIMD; 4 blocks/CU (8 waves), LDS 4x32KB = 128 KB.
// Flat 129/4 tile schedule and diagonal-skip logic unchanged from R13.
// vmcnt: 8 staging loads/wave -> steady queue [L_cur(8), atomic, L_next(8)]
// -> vmcnt(9); first tile vmcnt(8); tail vmcnt(1).
__global__ void __launch_bounds__(128, 2)
loss_kernel(const bf16* __restrict__ A, float* __restrict__ Tg) {
    __shared__ bf16 Bs0[32 * DIM];          // 16 KB
    __shared__ bf16 Bs1[32 * DIM];          // 16 KB

    const int tid = threadIdx.x;
    const int w  = tid >> 6;      // wave: rows w*64..+63 of the 128-row strip
    const int l  = tid & 63;
    const int lo = l & 31, hi = l >> 5;

    // flat tile range for this block (32 or 33 tiles)
    const int tbeg = (int)(((unsigned)blockIdx.x * 129u) >> 2);
    const int tend = (int)((((unsigned)blockIdx.x + 1u) * 129u) >> 2);
    const int nrem = tend - tbeg;

    // decode starting (it, jc): C(it) = 2*it*(257-it) <= tbeg < C(it+1)
    int it = 0;
    while (2 * (it + 1) * (257 - (it + 1)) <= tbeg) ++it;
    int jc = 4 * it + (tbeg - 2 * it * (257 - it));

    // persistent A fragments: af0 rows it*128+w*64+lo, af1 +32 (A-op: m=lo,
    // k=hi*8+j)
    bf16x8 af0[16], af1[16];
#define LOAD_AF                                                              \
    do {                                                                     \
        const bf16* ap_ = A + (size_t)(it * 128 + w * 64 + lo) * DIM + hi * 8; \
        _Pragma("unroll") for (int k_ = 0; k_ < 16; ++k_) {                  \
            af0[k_] = *(const volatile bf16x8*)(ap_ + k_ * 16);              \
            af1[k_] = *(const volatile bf16x8*)(ap_ + 32 * DIM + k_ * 16);   \
        }                                                                    \
    } while (0)
    LOAD_AF;

    float s0a[16], s0b[16];
#pragma unroll
    for (int r = 0; r < 16; ++r) { s0a[r] = 0.f; s0b[r] = 0.f; }

    // DMA lane constants. Wave w stages B-tile rows w*16..+15 in 8 instrs
    // (2 rows each). Lane: rl = l>>5 (row in pair), s = l&31 (LDS slot).
    // Slot s of row r holds global chunk c = (s&24)|((s&7)^(r&7)); row&7 =
    // (q*2+rl)&7 since w*16 is a multiple of 8.
    const int s_dma = l & 31;
    const int rl    = l >> 5;
    int vo[8];
#pragma unroll
    for (int q = 0; q < 8; ++q) {
        const int c = (s_dma & 24) | ((s_dma & 7) ^ ((q * 2 + rl) & 7));
        vo[q] = rl * DIM + c * 8;
    }

    // fragment-read constants: B row = lo; chunk cc at slot (cc&24)|((cc&7)^(lo&7))
    const int rbase = lo * DIM;
    const int mx7 = lo & 7;

#define ISSUE(jcn_, BUF)                                                     \
    do {                                                                     \
        const bf16* tb_ = A + (size_t)((jcn_) * 32 + w * 16) * DIM;          \
        bf16* lb_ = &BUF[(w * 16) * DIM];                                    \
        _Pragma("unroll") for (int q_ = 0; q_ < 8; ++q_) {                   \
            GLOAD_LDS(tb_ + (q_ * 2) * DIM + vo[q_],                         \
                      lb_ + (q_ * 2) * DIM);                                 \
        }                                                                    \
    } while (0)

#define FLUSH_ROWS                                                           \
    do {                                                                     \
        float tra_, trb_;                                                    \
        TREE16(s0a, tra_);                                                   \
        TREE16(s0b, trb_);                                                   \
        const int r_ = (lo >> 1) & 15;                                       \
        const int rowoff_ = (r_ & 3) + 8 * (r_ >> 2) + 4 * hi;               \
        if ((l & 1) == 0) {                                                  \
            atomicAdd(&Tg[it * 128 + w * 64 + rowoff_], tra_);               \
            atomicAdd(&Tg[it * 128 + w * 64 + 32 + rowoff_], trb_);          \
        }                                                                    \
    } while (0)

    int t = 0, jcn, itn;
    bool has_next;

#define NEXT_DECODE                                                          \
    do {                                                                     \
        has_next = (t + 1 < nrem);                                           \
        if (has_next) {                                                      \
            jcn = jc + 1; itn = it;                                          \
            if (jcn == NJC) { itn = it + 1; jcn = 4 * itn; }                 \
        } else { jcn = jc; itn = it; }                                       \
    } while (0)

    // WN = steady wait (next issued), WL = last-tile wait (no next issued)
#define TILE_BODY(BR, BW, WN, WL)                                            \
    do {                                                                     \
        asm volatile("s_barrier" ::: "memory");                              \
        if (has_next) {                                                      \
            ISSUE(jcn, BW);                                                  \
            asm volatile("s_waitcnt vmcnt(" #WN ")" ::: "memory");           \
        } else {                                                             \
            asm volatile("s_waitcnt vmcnt(" #WL ")" ::: "memory");           \
        }                                                                    \
        asm volatile("s_barrier" ::: "memory");                              \
        f32x16 c0a, c0b;                                                     \
        _Pragma("unroll") for (int r_ = 0; r_ < 16; ++r_) {                  \
            c0a[r_] = 0.f; c0b[r_] = 0.f;                                    \
        }                                                                    \
        __builtin_amdgcn_s_setprio(1);                                       \
        _Pragma("unroll") for (int k_ = 0; k_ < 16; ++k_) {                  \
            const int cc_ = k_ * 2 + hi;                                     \
            const int slot_ = (cc_ & 24) | ((cc_ & 7) ^ mx7);                \
            bf16x8 b_ = *(const bf16x8*)&BR[rbase + slot_ * 8];              \
            c0a = __builtin_amdgcn_mfma_f32_32x32x16_bf16(af0[k_], b_, c0a, 0, 0, 0); \
            c0b = __builtin_amdgcn_mfma_f32_32x32x16_bf16(af1[k_], b_, c0b, 0, 0, 0); \
        }                                                                    \
        __builtin_amdgcn_s_setprio(0);                                       \
        float cs_ = 0.f;                                                     \
        _Pragma("unroll") for (int r_ = 0; r_ < 16; ++r_) {                  \
            float ea_ = __builtin_amdgcn_exp2f(c0a[r_]);                     \
            s0a[r_] += ea_;                                                  \
            cs_ += ea_;                                                      \
        }                                                                    \
        _Pragma("unroll") for (int r_ = 0; r_ < 16; ++r_) {                  \
            float eb_ = __builtin_amdgcn_exp2f(c0b[r_]);                     \
            s0b[r_] += eb_;                                                  \
            cs_ += eb_;                                                      \
        }                                                                    \
        cs_ += __shfl_xor(cs_, 32);                                          \
        /* col-sum flush: UNCONDITIONAL instr (uniform vmcnt queue); adds  */ \
        /* 0.0 on the diagonal 128x128 block (covered by row sums).        */ \
        const float fv_ = ((jc >> 2) == it) ? 0.0f : cs_;                    \
        if (hi == 0) atomicAdd(&Tg[jc * 32 + lo], fv_);                      \
    } while (0)

    // advance to next tile; at it-segment boundary: flush row sums, reload af
#define ADVANCE                                                              \
    do {                                                                     \
        ++t;                                                                 \
        if (itn != it) {                                                     \
            FLUSH_ROWS;                                                      \
            it = itn;                                                        \
            LOAD_AF;                                                         \
            _Pragma("unroll") for (int r_ = 0; r_ < 16; ++r_) {              \
                s0a[r_] = 0.f; s0b[r_] = 0.f;                                \
            }                                                                \
        }                                                                    \
        jc = jcn;                                                            \
    } while (0)

    ISSUE(jc, Bs0);
    // peeled first tile: no atomic in the queue yet -> vmcnt(8)/(0)
    NEXT_DECODE;
    TILE_BODY(Bs0, Bs1, 8, 0);
    ADVANCE;
    while (t < nrem) {
        NEXT_DECODE;
        TILE_BODY(Bs1, Bs0, 9, 1);
        ADVANCE;
        if (t >= nrem) break;
        NEXT_DECODE;
        TILE_BODY(Bs0, Bs1, 9, 1);
        ADVANCE;
    }
    FLUSH_ROWS;

#undef ISSUE
#undef TILE_BODY
#undef NEXT_DECODE
#undef ADVANCE
#undef FLUSH_ROWS
#undef LOAD_AF
}

// Kernel 3: loss_i = ln2*(log2(T'_i) - s2'_i), mean over rows.
__global__ void __launch_bounds__(256) final_kernel(const float* __restrict__ Tg,
                                                    const float* __restrict__ Dg,
                                                    float* __restrict__ out) {
    __shared__ float red[4];
    const int i = blockIdx.x * 256 + threadIdx.x;
    float c = LN2F * (__log2f(Tg[i]) - Dg[i]) * (1.0f / (float)N_ROWS);
#pragma unroll
    for (int m = 1; m < 64; m <<= 1) c += __shfl_xor(c, m, 64);
    if ((threadIdx.x & 63) == 0) red[threadIdx.x >> 6] = c;
    __syncthreads();
    if (threadIdx.x == 0)
        atomicAdd(out, red[0] + red[1] + red[2] + red[3]);
}

extern "C" void kernel_launch(void* const* d_in, const int* in_sizes, int n_in,
                              void* d_out, int out_size, void* d_ws, size_t ws_size,
                              hipStream_t stream) {
    const float* emb = (const float*)d_in[0];
    float* out = (float*)d_out;
    bf16* Abf = (bf16*)d_ws;
    float* Tg = (float*)((char*)d_ws + WS_T_OFF);
    float* Dg = (float*)((char*)d_ws + WS_D_OFF);

    hipLaunchKernelGGL(normalize_kernel, dim3(N_ROWS / 4), dim3(256), 0, stream,
                       emb, Abf, Tg, Dg, out);
    hipLaunchKernelGGL(loss_kernel, dim3(NBLKS), dim3(128), 0, stream,
                       Abf, Tg);
    hipLaunchKernelGGL(final_kernel, dim3(N_ROWS / 256), dim3(256), 0, stream,
                       Tg, Dg, out);
}

// Round 5
// 168.413 us; speedup vs baseline: 1.3098x; 1.3098x over previous
//
#include <hip/hip_runtime.h>
#include <hip/hip_bf16.h>

typedef __bf16 bf16;
typedef __attribute__((ext_vector_type(8))) __bf16 bf16x8;
typedef __attribute__((ext_vector_type(4))) __bf16 bf16x4;
typedef __attribute__((ext_vector_type(16))) float f32x16;

#define N_ROWS 16384
#define DIM 256
#define NJC 512           /* 32-col tiles */
#define NBLKS 1024        /* 4 blocks/CU x 256 CU, one resident round */
#define NTILES 33024      /* sum_{it=0}^{127} (512-4it) */
#define SQK1 4.53981608f  /* sqrt(1/(0.07*ln2)): A pre-scaled so e^{z} = 2^{dot'} */
#define LN2F 0.69314718056f

#define WS_T_OFF (N_ROWS * DIM * 2)
#define WS_D_OFF (WS_T_OFF + N_ROWS * 4)

#define GLOAD_LDS(g, l)                                        \
    __builtin_amdgcn_global_load_lds(                          \
        (const __attribute__((address_space(1))) void*)(g),    \
        (__attribute__((address_space(3))) void*)(l), 16, 0, 0)

// Kernel 1: L2-normalize rows, scale by SQK1, emit bf16 A' to ws. Zeros T[]
// and d_out. Dg[row] = s2' = sum(bf16(SQK1*a)^2) = the MFMA diagonal, so the
// diagonal's bf16 rounding error cancels: loss_i = ln2*(log2(T'_i) - s2'_i).
__global__ void __launch_bounds__(256) normalize_kernel(const float* __restrict__ in,
                                                        bf16* __restrict__ out,
                                                        float* __restrict__ Tg,
                                                        float* __restrict__ Dg,
                                                        float* __restrict__ loss_out) {
    if (blockIdx.x == 0 && threadIdx.x == 0) loss_out[0] = 0.0f;
    if (blockIdx.x < 64) Tg[blockIdx.x * 256 + threadIdx.x] = 0.0f;

    const int row  = blockIdx.x * 4 + (threadIdx.x >> 6);
    const int lane = threadIdx.x & 63;
    const float4* rp = (const float4*)(in + (size_t)row * DIM);
    float4 v = rp[lane];
    float ss = v.x * v.x + v.y * v.y + v.z * v.z + v.w * v.w;
#pragma unroll
    for (int m = 1; m < 64; m <<= 1) ss += __shfl_xor(ss, m, 64);
    float inv = SQK1 / fmaxf(sqrtf(ss), 1e-12f);
    bf16x4 o;
    o[0] = (bf16)(v.x * inv);
    o[1] = (bf16)(v.y * inv);
    o[2] = (bf16)(v.z * inv);
    o[3] = (bf16)(v.w * inv);
    *(bf16x4*)(out + (size_t)row * DIM + lane * 4) = o;

    float f0 = (float)o[0], f1 = (float)o[1], f2 = (float)o[2], f3 = (float)o[3];
    float s2 = f0 * f0 + f1 * f1 + f2 * f2 + f3 * f3;
#pragma unroll
    for (int m = 1; m < 64; m <<= 1) s2 += __shfl_xor(s2, m, 64);
    if (lane == 0) Dg[row] = s2;
}

// Tree-reduce 16 floats across the 32 `lo` lanes; every lane ends with the
// full sum for register index r = (lo>>1)&15. (Correctness-proven R4-R10.)
#define TREE16(R, out)                                                     \
    do {                                                                   \
        float w8[8], w4[4], w2[2], w1, g_;                                 \
        _Pragma("unroll") for (int i_ = 0; i_ < 8; ++i_) {                 \
            g_ = (lo & 16) ? R[i_] : R[i_ + 8];                            \
            w8[i_] = ((lo & 16) ? R[i_ + 8] : R[i_]) + __shfl_xor(g_, 16); \
        }                                                                  \
        _Pragma("unroll") for (int i_ = 0; i_ < 4; ++i_) {                 \
            g_ = (lo & 8) ? w8[i_] : w8[i_ + 4];                           \
            w4[i_] = ((lo & 8) ? w8[i_ + 4] : w8[i_]) + __shfl_xor(g_, 8); \
        }                                                                  \
        _Pragma("unroll") for (int i_ = 0; i_ < 2; ++i_) {                 \
            g_ = (lo & 4) ? w4[i_] : w4[i_ + 2];                           \
            w2[i_] = ((lo & 4) ? w4[i_ + 2] : w4[i_]) + __shfl_xor(g_, 4); \
        }                                                                  \
        g_ = (lo & 2) ? w2[0] : w2[1];                                     \
        w1 = ((lo & 2) ? w2[1] : w2[0]) + __shfl_xor(g_, 2);               \
        out = w1 + __shfl_xor(w1, 1);                                      \
    } while (0)

// Kernel 2: symmetric A'A'^T + softmax denominator.
// R14 -> R15: SAME M_w=64 data path (proven: bank conflicts halved 8.45M ->
// 4.23M in R14), but fix the REGISTER ALLOCATION failure that spilled it:
// R14's launch_bounds(128,2) made the allocator snap to 128 VGPR and spill
// ~90 regs of af state to scratch (FETCH +74MB, WRITE +30MB, MfmaUtil 17%).
// Changes: (a) __launch_bounds__(128, 1) -> VGPR cap 512, allocator free to
// take the ~220 it needs (still <=256 -> 2 waves/SIMD -> 4 blocks/CU);
// (b) af loads no longer volatile -> live ranges schedulable/remat-able.
// Geometry (unchanged from R14): 2-wave blocks, wave owns TWO 32-row
// A-panels (af0/af1) sharing every b_ fragment across two MFMA chains ->
// 8B LDS read per output (was 16B in R13). Flat 129/4 schedule, diagonal
// skip, vmcnt(9/8/1) windows all unchanged (R14 passed correctness).
__global__ void __launch_bounds__(128, 1)
loss_kernel(const bf16* __restrict__ A, float* __restrict__ Tg) {
    __shared__ bf16 Bs0[32 * DIM];          // 16 KB
    __shared__ bf16 Bs1[32 * DIM];          // 16 KB

    const int tid = threadIdx.x;
    const int w  = tid >> 6;      // wave: rows w*64..+63 of the 128-row strip
    const int l  = tid & 63;
    const int lo = l & 31, hi = l >> 5;

    // flat tile range for this block (32 or 33 tiles)
    const int tbeg = (int)(((unsigned)blockIdx.x * 129u) >> 2);
    const int tend = (int)((((unsigned)blockIdx.x + 1u) * 129u) >> 2);
    const int nrem = tend - tbeg;

    // decode starting (it, jc): C(it) = 2*it*(257-it) <= tbeg < C(it+1)
    int it = 0;
    while (2 * (it + 1) * (257 - (it + 1)) <= tbeg) ++it;
    int jc = 4 * it + (tbeg - 2 * it * (257 - it));

    // persistent A fragments: af0 rows it*128+w*64+lo, af1 +32 (A-op: m=lo,
    // k=hi*8+j)
    bf16x8 af0[16], af1[16];
#define LOAD_AF                                                              \
    do {                                                                     \
        const bf16* ap_ = A + (size_t)(it * 128 + w * 64 + lo) * DIM + hi * 8; \
        _Pragma("unroll") for (int k_ = 0; k_ < 16; ++k_) {                  \
            af0[k_] = *(const bf16x8*)(ap_ + k_ * 16);                       \
            af1[k_] = *(const bf16x8*)(ap_ + 32 * DIM + k_ * 16);            \
        }                                                                    \
    } while (0)
    LOAD_AF;

    float s0a[16], s0b[16];
#pragma unroll
    for (int r = 0; r < 16; ++r) { s0a[r] = 0.f; s0b[r] = 0.f; }

    // DMA lane constants. Wave w stages B-tile rows w*16..+15 in 8 instrs
    // (2 rows each). Lane: rl = l>>5 (row in pair), s = l&31 (LDS slot).
    // Slot s of row r holds global chunk c = (s&24)|((s&7)^(r&7)); row&7 =
    // (q*2+rl)&7 since w*16 is a multiple of 8.
    const int s_dma = l & 31;
    const int rl    = l >> 5;
    int vo[8];
#pragma unroll
    for (int q = 0; q < 8; ++q) {
        const int c = (s_dma & 24) | ((s_dma & 7) ^ ((q * 2 + rl) & 7));
        vo[q] = rl * DIM + c * 8;
    }

    // fragment-read constants: B row = lo; chunk cc at slot (cc&24)|((cc&7)^(lo&7))
    const int rbase = lo * DIM;
    const int mx7 = lo & 7;

#define ISSUE(jcn_, BUF)                                                     \
    do {                                                                     \
        const bf16* tb_ = A + (size_t)((jcn_) * 32 + w * 16) * DIM;          \
        bf16* lb_ = &BUF[(w * 16) * DIM];                                    \
        _Pragma("unroll") for (int q_ = 0; q_ < 8; ++q_) {                   \
            GLOAD_LDS(tb_ + (q_ * 2) * DIM + vo[q_],                         \
                      lb_ + (q_ * 2) * DIM);                                 \
        }                                                                    \
    } while (0)

#define FLUSH_ROWS                                                           \
    do {                                                                     \
        float tra_, trb_;                                                    \
        TREE16(s0a, tra_);                                                   \
        TREE16(s0b, trb_);                                                   \
        const int r_ = (lo >> 1) & 15;                                       \
        const int rowoff_ = (r_ & 3) + 8 * (r_ >> 2) + 4 * hi;               \
        if ((l & 1) == 0) {                                                  \
            atomicAdd(&Tg[it * 128 + w * 64 + rowoff_], tra_);               \
            atomicAdd(&Tg[it * 128 + w * 64 + 32 + rowoff_], trb_);          \
        }                                                                    \
    } while (0)

    int t = 0, jcn, itn;
    bool has_next;

#define NEXT_DECODE                                                          \
    do {                                                                     \
        has_next = (t + 1 < nrem);                                           \
        if (has_next) {                                                      \
            jcn = jc + 1; itn = it;                                          \
            if (jcn == NJC) { itn = it + 1; jcn = 4 * itn; }                 \
        } else { jcn = jc; itn = it; }                                       \
    } while (0)

    // WN = steady wait (next issued), WL = last-tile wait (no next issued)
#define TILE_BODY(BR, BW, WN, WL)                                            \
    do {                                                                     \
        asm volatile("s_barrier" ::: "memory");                              \
        if (has_next) {                                                      \
            ISSUE(jcn, BW);                                                  \
            asm volatile("s_waitcnt vmcnt(" #WN ")" ::: "memory");           \
        } else {                                                             \
            asm volatile("s_waitcnt vmcnt(" #WL ")" ::: "memory");           \
        }                                                                    \
        asm volatile("s_barrier" ::: "memory");                              \
        f32x16 c0a, c0b;                                                     \
        _Pragma("unroll") for (int r_ = 0; r_ < 16; ++r_) {                  \
            c0a[r_] = 0.f; c0b[r_] = 0.f;                                    \
        }                                                                    \
        __builtin_amdgcn_s_setprio(1);                                       \
        _Pragma("unroll") for (int k_ = 0; k_ < 16; ++k_) {                  \
            const int cc_ = k_ * 2 + hi;                                     \
            const int slot_ = (cc_ & 24) | ((cc_ & 7) ^ mx7);                \
            bf16x8 b_ = *(const bf16x8*)&BR[rbase + slot_ * 8];              \
            c0a = __builtin_amdgcn_mfma_f32_32x32x16_bf16(af0[k_], b_, c0a, 0, 0, 0); \
            c0b = __builtin_amdgcn_mfma_f32_32x32x16_bf16(af1[k_], b_, c0b, 0, 0, 0); \
        }                                                                    \
        __builtin_amdgcn_s_setprio(0);                                       \
        float cs_ = 0.f;                                                     \
        _Pragma("unroll") for (int r_ = 0; r_ < 16; ++r_) {                  \
            float ea_ = __builtin_amdgcn_exp2f(c0a[r_]);                     \
            s0a[r_] += ea_;                                                  \
            cs_ += ea_;                                                      \
        }                                                                    \
        _Pragma("unroll") for (int r_ = 0; r_ < 16; ++r_) {                  \
            float eb_ = __builtin_amdgcn_exp2f(c0b[r_]);                     \
            s0b[r_] += eb_;                                                  \
            cs_ += eb_;                                                      \
        }                                                                    \
        cs_ += __shfl_xor(cs_, 32);                                          \
        /* col-sum flush: UNCONDITIONAL instr (uniform vmcnt queue); adds  */ \
        /* 0.0 on the diagonal 128x128 block (covered by row sums).        */ \
        const float fv_ = ((jc >> 2) == it) ? 0.0f : cs_;                    \
        if (hi == 0) atomicAdd(&Tg[jc * 32 + lo], fv_);                      \
    } while (0)

    // advance to next tile; at it-segment boundary: flush row sums, reload af
#define ADVANCE                                                              \
    do {                                                                     \
        ++t;                                                                 \
        if (itn != it) {                                                     \
            FLUSH_ROWS;                                                      \
            it = itn;                                                        \
            LOAD_AF;                                                         \
            _Pragma("unroll") for (int r_ = 0; r_ < 16; ++r_) {              \
                s0a[r_] = 0.f; s0b[r_] = 0.f;                                \
            }                                                                \
        }                                                                    \
        jc = jcn;                                                            \
    } while (0)

    ISSUE(jc, Bs0);
    // peeled first tile: no atomic in the queue yet -> vmcnt(8)/(0)
    NEXT_DECODE;
    TILE_BODY(Bs0, Bs1, 8, 0);
    ADVANCE;
    while (t < nrem) {
        NEXT_DECODE;
        TILE_BODY(Bs1, Bs0, 9, 1);
        ADVANCE;
        if (t >= nrem) break;
        NEXT_DECODE;
        TILE_BODY(Bs0, Bs1, 9, 1);
        ADVANCE;
    }
    FLUSH_ROWS;

#undef ISSUE
#undef TILE_BODY
#undef NEXT_DECODE
#undef ADVANCE
#undef FLUSH_ROWS
#undef LOAD_AF
}

// Kernel 3: loss_i = ln2*(log2(T'_i) - s2'_i), mean over rows.
__global__ void __launch_bounds__(256) final_kernel(const float* __restrict__ Tg,
                                                    const float* __restrict__ Dg,
                                                    float* __restrict__ out) {
    __shared__ float red[4];
    const int i = blockIdx.x * 256 + threadIdx.x;
    float c = LN2F * (__log2f(Tg[i]) - Dg[i]) * (1.0f / (float)N_ROWS);
#pragma unroll
    for (int m = 1; m < 64; m <<= 1) c += __shfl_xor(c, m, 64);
    if ((threadIdx.x & 63) == 0) red[threadIdx.x >> 6] = c;
    __syncthreads();
    if (threadIdx.x == 0)
        atomicAdd(out, red[0] + red[1] + red[2] + red[3]);
}

extern "C" void kernel_launch(void* const* d_in, const int* in_sizes, int n_in,
                              void* d_out, int out_size, void* d_ws, size_t ws_size,
                              hipStream_t stream) {
    const float* emb = (const float*)d_in[0];
    float* out = (float*)d_out;
    bf16* Abf = (bf16*)d_ws;
    float* Tg = (float*)((char*)d_ws + WS_T_OFF);
    float* Dg = (float*)((char*)d_ws + WS_D_OFF);

    hipLaunchKernelGGL(normalize_kernel, dim3(N_ROWS / 4), dim3(256), 0, stream,
                       emb, Abf, Tg, Dg, out);
    hipLaunchKernelGGL(loss_kernel, dim3(NBLKS), dim3(128), 0, stream,
                       Abf, Tg);
    hipLaunchKernelGGL(final_kernel, dim3(N_ROWS / 256), dim3(256), 0, stream,
                       Tg, Dg, out);
}

// Round 6
// 157.624 us; speedup vs baseline: 1.3994x; 1.0684x over previous
//
#include <hip/hip_runtime.h>
#include <hip/hip_bf16.h>

typedef __bf16 bf16;
typedef __attribute__((ext_vector_type(8))) __bf16 bf16x8;
typedef __attribute__((ext_vector_type(4))) __bf16 bf16x4;
typedef __attribute__((ext_vector_type(16))) float f32x16;

#define N_ROWS 16384
#define DIM 256
#define NJC 512           /* 32-col tiles */
#define NBLKS 1024        /* 4 blocks/CU x 256 CU, one resident round */
#define NTILES 33024      /* sum_{it=0}^{127} (512-4it) */
#define SQK1 4.53981608f  /* sqrt(1/(0.07*ln2)): A pre-scaled so e^{z} = 2^{dot'} */
#define LN2F 0.69314718056f

#define WS_T_OFF (N_ROWS * DIM * 2)
#define WS_D_OFF (WS_T_OFF + N_ROWS * 4)

#define GLOAD_LDS(g, l)                                        \
    __builtin_amdgcn_global_load_lds(                          \
        (const __attribute__((address_space(1))) void*)(g),    \
        (__attribute__((address_space(3))) void*)(l), 16, 0, 0)

// Kernel 1: L2-normalize rows, scale by SQK1, emit bf16 A' to ws. Zeros T[]
// and d_out. Dg[row] = s2' = sum(bf16(SQK1*a)^2) = the MFMA diagonal, so the
// diagonal's bf16 rounding error cancels: loss_i = ln2*(log2(T'_i) - s2'_i).
__global__ void __launch_bounds__(256) normalize_kernel(const float* __restrict__ in,
                                                        bf16* __restrict__ out,
                                                        float* __restrict__ Tg,
                                                        float* __restrict__ Dg,
                                                        float* __restrict__ loss_out) {
    if (blockIdx.x == 0 && threadIdx.x == 0) loss_out[0] = 0.0f;
    if (blockIdx.x < 64) Tg[blockIdx.x * 256 + threadIdx.x] = 0.0f;

    const int row  = blockIdx.x * 4 + (threadIdx.x >> 6);
    const int lane = threadIdx.x & 63;
    const float4* rp = (const float4*)(in + (size_t)row * DIM);
    float4 v = rp[lane];
    float ss = v.x * v.x + v.y * v.y + v.z * v.z + v.w * v.w;
#pragma unroll
    for (int m = 1; m < 64; m <<= 1) ss += __shfl_xor(ss, m, 64);
    float inv = SQK1 / fmaxf(sqrtf(ss), 1e-12f);
    bf16x4 o;
    o[0] = (bf16)(v.x * inv);
    o[1] = (bf16)(v.y * inv);
    o[2] = (bf16)(v.z * inv);
    o[3] = (bf16)(v.w * inv);
    *(bf16x4*)(out + (size_t)row * DIM + lane * 4) = o;

    float f0 = (float)o[0], f1 = (float)o[1], f2 = (float)o[2], f3 = (float)o[3];
    float s2 = f0 * f0 + f1 * f1 + f2 * f2 + f3 * f3;
#pragma unroll
    for (int m = 1; m < 64; m <<= 1) s2 += __shfl_xor(s2, m, 64);
    if (lane == 0) Dg[row] = s2;
}

// Tree-reduce 16 floats across the 32 `lo` lanes; every lane ends with the
// full sum for register index r = (lo>>1)&15. (Correctness-proven R4-R10.)
#define TREE16(R, out)                                                     \
    do {                                                                   \
        float w8[8], w4[4], w2[2], w1, g_;                                 \
        _Pragma("unroll") for (int i_ = 0; i_ < 8; ++i_) {                 \
            g_ = (lo & 16) ? R[i_] : R[i_ + 8];                            \
            w8[i_] = ((lo & 16) ? R[i_ + 8] : R[i_]) + __shfl_xor(g_, 16); \
        }                                                                  \
        _Pragma("unroll") for (int i_ = 0; i_ < 4; ++i_) {                 \
            g_ = (lo & 8) ? w8[i_] : w8[i_ + 4];                           \
            w4[i_] = ((lo & 8) ? w8[i_ + 4] : w8[i_]) + __shfl_xor(g_, 8); \
        }                                                                  \
        _Pragma("unroll") for (int i_ = 0; i_ < 2; ++i_) {                 \
            g_ = (lo & 4) ? w4[i_] : w4[i_ + 2];                           \
            w2[i_] = ((lo & 4) ? w4[i_ + 2] : w4[i_]) + __shfl_xor(g_, 4); \
        }                                                                  \
        g_ = (lo & 2) ? w2[0] : w2[1];                                     \
        w1 = ((lo & 2) ? w2[1] : w2[0]) + __shfl_xor(g_, 2);               \
        out = w1 + __shfl_xor(w1, 1);                                      \
    } while (0)

// Kernel 2: symmetric A'A'^T + softmax denominator.
// R15 -> R16: back to R13's proven geometry (M_w=32, 4-wave/256-thr blocks,
// ~64 VGPR class; the M_w=64 path is allocator-infeasible: R14 spilled at
// cap 256, R15 took 316 regs -> 1 wave/SIMD, 9% occupancy). New: DUAL-ACC
// SOFTWARE PIPELINE — tile t's MFMA k-loop (LDS+MFMA pipes) is fused with
// tile t-1's exp2 epilogue (VALU/trans pipe): one exp2-pair per k-step
// fills the ds_read/MFMA stall slots. R13's per-tile serial structure
// [k-loop | epilogue] left each pipe idle half the time; fusion overlaps
// them within one wave. Cost: +16 regs (second f32x16 acc) -> ~145 total,
// expect 3 waves/SIMD. Flat 129/4 schedule, DMA swizzle, diag-skip, vmcnt
// windows (4/4/5...5/1) carried from R13; setprio dropped (MFMA and epi
// VALU are now intentionally interleaved).
__global__ void __launch_bounds__(256, 1)
loss_kernel(const bf16* __restrict__ A, float* __restrict__ Tg) {
    __shared__ bf16 Bs0[32 * DIM];          // 16 KB
    __shared__ bf16 Bs1[32 * DIM];          // 16 KB

    const int tid = threadIdx.x;
    const int w  = tid >> 6;      // wave = row-group: rows w*32..+31 of the 128-row strip
    const int l  = tid & 63;
    const int lo = l & 31, hi = l >> 5;

    // flat tile range for this block (32 or 33 tiles)
    const int tbeg = (int)(((unsigned)blockIdx.x * 129u) >> 2);
    const int tend = (int)((((unsigned)blockIdx.x + 1u) * 129u) >> 2);
    const int nrem = tend - tbeg;

    // decode starting (it, jc): C(it) = 2*it*(257-it) <= tbeg < C(it+1)
    int it = 0;
    while (2 * (it + 1) * (257 - (it + 1)) <= tbeg) ++it;
    int jc = 4 * it + (tbeg - 2 * it * (257 - it));

    // persistent A fragments for the wave's 32 rows (A-op: m=lo, k=hi*8+j)
    bf16x8 af[16];
#define LOAD_AF(ITX)                                                         \
    do {                                                                     \
        const bf16* ap_ = A + (size_t)((ITX) * 128 + w * 32 + lo) * DIM + hi * 8; \
        _Pragma("unroll") for (int k_ = 0; k_ < 16; ++k_)                    \
            af[k_] = *(const bf16x8*)(ap_ + k_ * 16);                        \
    } while (0)
    LOAD_AF(it);

    float s0[16];
#pragma unroll
    for (int r = 0; r < 16; ++r) s0[r] = 0.f;

    // DMA lane constants. Wave w stages B-tile rows w*8..+7 in 4 instrs
    // (2 rows each). Lane: rl = l>>5 (row in pair), s = l&31 (LDS slot).
    // Slot s of row r holds global chunk c = (s&24)|((s&7)^(r&7)).
    const int s_dma = l & 31;
    const int rl    = l >> 5;
    int vo[4];
#pragma unroll
    for (int q = 0; q < 4; ++q) {
        const int c = (s_dma & 24) | ((s_dma & 7) ^ ((q * 2 + rl) & 7));
        vo[q] = rl * DIM + c * 8;
    }

    // fragment-read constants: B row = lo; chunk cc at slot (cc&24)|((cc&7)^(lo&7))
    const int rbase = lo * DIM;
    const int mx7 = lo & 7;

#define ISSUE(jcn_, BUF)                                                     \
    do {                                                                     \
        const bf16* tb_ = A + (size_t)((jcn_) * 32 + w * 8) * DIM;           \
        bf16* lb_ = &BUF[(w * 8) * DIM];                                     \
        _Pragma("unroll") for (int q_ = 0; q_ < 4; ++q_) {                   \
            GLOAD_LDS(tb_ + (q_ * 2) * DIM + vo[q_],                         \
                      lb_ + (q_ * 2) * DIM);                                 \
        }                                                                    \
    } while (0)

#define FLUSH_ROWS(ITP)                                                      \
    do {                                                                     \
        float tr_;                                                           \
        TREE16(s0, tr_);                                                     \
        const int r_ = (lo >> 1) & 15;                                       \
        const int rowoff_ = (r_ & 3) + 8 * (r_ >> 2) + 4 * hi;               \
        if ((l & 1) == 0)                                                    \
            atomicAdd(&Tg[(ITP) * 128 + w * 32 + rowoff_], tr_);             \
    } while (0)

    int t = 0, jcn, itn;
    int itP = it, jcP = jc;   // tile held in the "old" accumulator
    bool has_next;

#define NEXT_DECODE                                                          \
    do {                                                                     \
        has_next = (t + 1 < nrem);                                           \
        if (has_next) {                                                      \
            jcn = jc + 1; itn = it;                                          \
            if (jcn == NJC) { itn = it + 1; jcn = 4 * itn; }                 \
        } else { jcn = jc; itn = it; }                                       \
    } while (0)

    // Barrier + prefetch-issue + counted-vmcnt prologue of a step.
#define STEP_SYNC(BW, WN, WL)                                                \
    do {                                                                     \
        asm volatile("s_barrier" ::: "memory");                              \
        if (has_next) {                                                      \
            ISSUE(jcn, BW);                                                  \
            asm volatile("s_waitcnt vmcnt(" #WN ")" ::: "memory");           \
        } else {                                                             \
            asm volatile("s_waitcnt vmcnt(" #WL ")" ::: "memory");           \
        }                                                                    \
        asm volatile("s_barrier" ::: "memory");                              \
    } while (0)

    // Shared tail of a step: advance tile indices, reload af at strip change.
#define STEP_ADVANCE                                                         \
    do {                                                                     \
        itP = it; jcP = jc;                                                  \
        if (itn != it) LOAD_AF(itn);                                         \
        it = itn; jc = jcn; ++t;                                             \
    } while (0)

    // First tile: k-loop only, no epilogue to fuse.
#define STEP_NOEPI(BR, BW, CN, WN, WL)                                       \
    do {                                                                     \
        NEXT_DECODE;                                                         \
        STEP_SYNC(BW, WN, WL);                                               \
        _Pragma("unroll") for (int r_ = 0; r_ < 16; ++r_) CN[r_] = 0.f;      \
        _Pragma("unroll") for (int k_ = 0; k_ < 16; ++k_) {                  \
            const int cc_ = k_ * 2 + hi;                                     \
            const int slot_ = (cc_ & 24) | ((cc_ & 7) ^ mx7);                \
            bf16x8 b_ = *(const bf16x8*)&BR[rbase + slot_ * 8];              \
            CN = __builtin_amdgcn_mfma_f32_32x32x16_bf16(af[k_], b_, CN, 0, 0, 0); \
        }                                                                    \
        STEP_ADVANCE;                                                        \
    } while (0)

    // Steady step: MFMA k-loop for tile (it,jc) into CN fused with the exp2
    // epilogue of tile (itP,jcP) held in CO (2 exps per k-step, separate
    // pipes). Then col-flush of (itP,jcP) and strip flush if itP closes.
#define STEP_EPI(BR, BW, CN, CO, WN, WL)                                     \
    do {                                                                     \
        NEXT_DECODE;                                                         \
        STEP_SYNC(BW, WN, WL);                                               \
        _Pragma("unroll") for (int r_ = 0; r_ < 16; ++r_) CN[r_] = 0.f;      \
        float cs_ = 0.f;                                                     \
        _Pragma("unroll") for (int k_ = 0; k_ < 16; ++k_) {                  \
            const int cc_ = k_ * 2 + hi;                                     \
            const int slot_ = (cc_ & 24) | ((cc_ & 7) ^ mx7);                \
            bf16x8 b_ = *(const bf16x8*)&BR[rbase + slot_ * 8];              \
            CN = __builtin_amdgcn_mfma_f32_32x32x16_bf16(af[k_], b_, CN, 0, 0, 0); \
            float e0_ = __builtin_amdgcn_exp2f(CO[2 * k_]);                  \
            float e1_ = __builtin_amdgcn_exp2f(CO[2 * k_ + 1]);              \
            s0[2 * k_]     += e0_;                                           \
            s0[2 * k_ + 1] += e1_;                                           \
            cs_ += e0_ + e1_;                                                \
        }                                                                    \
        cs_ += __shfl_xor(cs_, 32);                                          \
        const float fv_ = ((jcP >> 2) == itP) ? 0.0f : cs_;                  \
        if (hi == 0) atomicAdd(&Tg[jcP * 32 + lo], fv_);                     \
        if (itP != it) {                                                     \
            FLUSH_ROWS(itP);                                                 \
            _Pragma("unroll") for (int r_ = 0; r_ < 16; ++r_) s0[r_] = 0.f;  \
        }                                                                    \
        STEP_ADVANCE;                                                        \
    } while (0)

    // Drain the final accumulator (tile (itP,jcP) after the last step).
#define DRAIN(CO)                                                            \
    do {                                                                     \
        float cs_ = 0.f;                                                     \
        _Pragma("unroll") for (int r_ = 0; r_ < 16; ++r_) {                  \
            float e_ = __builtin_amdgcn_exp2f(CO[r_]);                       \
            s0[r_] += e_;                                                    \
            cs_ += e_;                                                       \
        }                                                                    \
        cs_ += __shfl_xor(cs_, 32);                                          \
        const float fv_ = ((jcP >> 2) == itP) ? 0.0f : cs_;                  \
        if (hi == 0) atomicAdd(&Tg[jcP * 32 + lo], fv_);                     \
    } while (0)

    f32x16 cA, cB;

    ISSUE(jc, Bs0);
    // t=0: queue [L0(4), L1(4)] -> vmcnt(4) retires L0. No epilogue yet.
    STEP_NOEPI(Bs0, Bs1, cA, 4, 0);
    // t=1: queue [L1(4), L2(4)] (no atomic yet) -> vmcnt(4).
    STEP_EPI(Bs1, Bs0, cB, cA, 4, 0);
    // t>=2 steady: queue [L_t(4), A(t-2), L_{t+1}(4)] -> vmcnt(5); tail 1.
    while (t < nrem) {
        STEP_EPI(Bs0, Bs1, cA, cB, 5, 1);          // t even
        if (t >= nrem) break;
        STEP_EPI(Bs1, Bs0, cB, cA, 5, 1);          // t odd
    }
    // last tile's acc: cA if nrem odd (last t even), else cB
    if (nrem & 1) DRAIN(cA); else DRAIN(cB);
    FLUSH_ROWS(itP);

#undef ISSUE
#undef STEP_SYNC
#undef STEP_ADVANCE
#undef STEP_NOEPI
#undef STEP_EPI
#undef DRAIN
#undef NEXT_DECODE
#undef FLUSH_ROWS
#undef LOAD_AF
}

// Kernel 3: loss_i = ln2*(log2(T'_i) - s2'_i), mean over rows.
__global__ void __launch_bounds__(256) final_kernel(const float* __restrict__ Tg,
                                                    const float* __restrict__ Dg,
                                                    float* __restrict__ out) {
    __shared__ float red[4];
    const int i = blockIdx.x * 256 + threadIdx.x;
    float c = LN2F * (__log2f(Tg[i]) - Dg[i]) * (1.0f / (float)N_ROWS);
#pragma unroll
    for (int m = 1; m < 64; m <<= 1) c += __shfl_xor(c, m, 64);
    if ((threadIdx.x & 63) == 0) red[threadIdx.x >> 6] = c;
    __syncthreads();
    if (threadIdx.x == 0)
        atomicAdd(out, red[0] + red[1] + red[2] + red[3]);
}

extern "C" void kernel_launch(void* const* d_in, const int* in_sizes, int n_in,
                              void* d_out, int out_size, void* d_ws, size_t ws_size,
                              hipStream_t stream) {
    const float* emb = (const float*)d_in[0];
    float* out = (float*)d_out;
    bf16* Abf = (bf16*)d_ws;
    float* Tg = (float*)((char*)d_ws + WS_T_OFF);
    float* Dg = (float*)((char*)d_ws + WS_D_OFF);

    hipLaunchKernelGGL(normalize_kernel, dim3(N_ROWS / 4), dim3(256), 0, stream,
                       emb, Abf, Tg, Dg, out);
    hipLaunchKernelGGL(loss_kernel, dim3(NBLKS), dim3(256), 0, stream,
                       Abf, Tg);
    hipLaunchKernelGGL(final_kernel, dim3(N_ROWS / 256), dim3(256), 0, stream,
                       Tg, Dg, out);
}

// Round 7
// 145.842 us; speedup vs baseline: 1.5125x; 1.0808x over previous
//
#include <hip/hip_runtime.h>
#include <hip/hip_bf16.h>

typedef __bf16 bf16;
typedef __attribute__((ext_vector_type(8))) __bf16 bf16x8;
typedef __attribute__((ext_vector_type(4))) __bf16 bf16x4;
typedef __attribute__((ext_vector_type(16))) float f32x16;

#define N_ROWS 16384
#define DIM 256
#define NJC 512           /* 32-col tiles */
#define NBLKS 768         /* 3 blocks/CU x 256 CU = exact residency (regs cap
                             us at 3 waves/SIMD; R13's 1024 ran a 33% serial
                             over-round per CU) */
#define TPB 43            /* 33024 / 768 exactly */
#define NTILES 33024      /* sum_{it=0}^{127} (512-4it) */
#define SQK1 4.53981608f  /* sqrt(1/(0.07*ln2)): A pre-scaled so e^{z} = 2^{dot'} */
#define LN2F 0.69314718056f

#define WS_T_OFF (N_ROWS * DIM * 2)
#define WS_D_OFF (WS_T_OFF + N_ROWS * 4)

#define GLOAD_LDS(g, l)                                        \
    __builtin_amdgcn_global_load_lds(                          \
        (const __attribute__((address_space(1))) void*)(g),    \
        (__attribute__((address_space(3))) void*)(l), 16, 0, 0)

// Kernel 1: L2-normalize rows, scale by SQK1, emit bf16 A' to ws. Zeros T[]
// and d_out. Dg[row] = s2' = sum(bf16(SQK1*a)^2) = the MFMA diagonal, so the
// diagonal's bf16 rounding error cancels: loss_i = ln2*(log2(T'_i) - s2'_i).
__global__ void __launch_bounds__(256) normalize_kernel(const float* __restrict__ in,
                                                        bf16* __restrict__ out,
                                                        float* __restrict__ Tg,
                                                        float* __restrict__ Dg,
                                                        float* __restrict__ loss_out) {
    if (blockIdx.x == 0 && threadIdx.x == 0) loss_out[0] = 0.0f;
    if (blockIdx.x < 64) Tg[blockIdx.x * 256 + threadIdx.x] = 0.0f;

    const int row  = blockIdx.x * 4 + (threadIdx.x >> 6);
    const int lane = threadIdx.x & 63;
    const float4* rp = (const float4*)(in + (size_t)row * DIM);
    float4 v = rp[lane];
    float ss = v.x * v.x + v.y * v.y + v.z * v.z + v.w * v.w;
#pragma unroll
    for (int m = 1; m < 64; m <<= 1) ss += __shfl_xor(ss, m, 64);
    float inv = SQK1 / fmaxf(sqrtf(ss), 1e-12f);
    bf16x4 o;
    o[0] = (bf16)(v.x * inv);
    o[1] = (bf16)(v.y * inv);
    o[2] = (bf16)(v.z * inv);
    o[3] = (bf16)(v.w * inv);
    *(bf16x4*)(out + (size_t)row * DIM + lane * 4) = o;

    float f0 = (float)o[0], f1 = (float)o[1], f2 = (float)o[2], f3 = (float)o[3];
    float s2 = f0 * f0 + f1 * f1 + f2 * f2 + f3 * f3;
#pragma unroll
    for (int m = 1; m < 64; m <<= 1) s2 += __shfl_xor(s2, m, 64);
    if (lane == 0) Dg[row] = s2;
}

// Tree-reduce 16 floats across the 32 `lo` lanes; every lane ends with the
// full sum for register index r = (lo>>1)&15. (Correctness-proven R4-R10.)
#define TREE16(R, out)                                                     \
    do {                                                                   \
        float w8[8], w4[4], w2[2], w1, g_;                                 \
        _Pragma("unroll") for (int i_ = 0; i_ < 8; ++i_) {                 \
            g_ = (lo & 16) ? R[i_] : R[i_ + 8];                            \
            w8[i_] = ((lo & 16) ? R[i_ + 8] : R[i_]) + __shfl_xor(g_, 16); \
        }                                                                  \
        _Pragma("unroll") for (int i_ = 0; i_ < 4; ++i_) {                 \
            g_ = (lo & 8) ? w8[i_] : w8[i_ + 4];                           \
            w4[i_] = ((lo & 8) ? w8[i_ + 4] : w8[i_]) + __shfl_xor(g_, 8); \
        }                                                                  \
        _Pragma("unroll") for (int i_ = 0; i_ < 2; ++i_) {                 \
            g_ = (lo & 4) ? w4[i_] : w4[i_ + 2];                           \
            w2[i_] = ((lo & 4) ? w4[i_ + 2] : w4[i_]) + __shfl_xor(g_, 4); \
        }                                                                  \
        g_ = (lo & 2) ? w2[0] : w2[1];                                     \
        w1 = ((lo & 2) ? w2[1] : w2[0]) + __shfl_xor(g_, 2);               \
        out = w1 + __shfl_xor(w1, 1);                                      \
    } while (0)

// Kernel 2: symmetric A'A'^T + softmax denominator.
// R16 -> R17: revert R16's fused epilogue (it cost +40 VGPR -> occupancy
// 18.5%, dur 105 us). Back to R13's exact data path (VGPR 64, 3 waves/SIMD),
// with ONE change: NBLKS 1024 -> 768. Registers cap residency at 3 blocks/CU
// (64 VGPR + ~80 AGPR = ~144 of 512), so R13's 4 blocks/CU grid ran a 33%
// serial over-round per CU — predicted timeavg occupancy (0.75*37.5 +
// 0.25*12.5) = 31.25% matches the measured 32%. Now 768 = 3/CU exactly
// resident from t=0, each block owns exactly 43 tiles (33024/768, flat
// contiguous range, zero imbalance). All sync/vmcnt/DMA/swizzle identical
// to R13 (correctness-passing).
__global__ void __launch_bounds__(256, 3)
loss_kernel(const bf16* __restrict__ A, float* __restrict__ Tg) {
    __shared__ bf16 Bs0[32 * DIM];          // 16 KB
    __shared__ bf16 Bs1[32 * DIM];          // 16 KB

    const int tid = threadIdx.x;
    const int w  = tid >> 6;      // wave = row-group: rows w*32..+31 of the 128-row strip
    const int l  = tid & 63;
    const int lo = l & 31, hi = l >> 5;

    // flat tile range for this block: exactly TPB tiles
    const int tbeg = blockIdx.x * TPB;
    const int nrem = TPB;

    // decode starting (it, jc): C(it) = 2*it*(257-it) <= tbeg < C(it+1)
    int it = 0;
    while (2 * (it + 1) * (257 - (it + 1)) <= tbeg) ++it;
    int jc = 4 * it + (tbeg - 2 * it * (257 - it));

    // persistent A fragments for the wave's 32 rows (A-op: m=lo, k=hi*8+j)
    bf16x8 af[16];
#define LOAD_AF                                                              \
    do {                                                                     \
        const bf16* ap_ = A + (size_t)(it * 128 + w * 32 + lo) * DIM + hi * 8; \
        _Pragma("unroll") for (int k_ = 0; k_ < 16; ++k_)                    \
            af[k_] = *(const bf16x8*)(ap_ + k_ * 16);                        \
    } while (0)
    LOAD_AF;

    float s0[16];
#pragma unroll
    for (int r = 0; r < 16; ++r) s0[r] = 0.f;

    // DMA lane constants. Wave w stages B-tile rows w*8..+7 in 4 instrs
    // (2 rows each). Lane: rl = l>>5 (row in pair), s = l&31 (LDS slot).
    // Slot s of row r holds global chunk c = (s&24)|((s&7)^(r&7)).
    const int s_dma = l & 31;
    const int rl    = l >> 5;
    int vo[4];
#pragma unroll
    for (int q = 0; q < 4; ++q) {
        const int c = (s_dma & 24) | ((s_dma & 7) ^ ((q * 2 + rl) & 7));
        vo[q] = rl * DIM + c * 8;
    }

    // fragment-read constants: B row = lo; chunk cc at slot (cc&24)|((cc&7)^(lo&7))
    const int rbase = lo * DIM;
    const int mx7 = lo & 7;

#define ISSUE(jcn_, BUF)                                                     \
    do {                                                                     \
        const bf16* tb_ = A + (size_t)((jcn_) * 32 + w * 8) * DIM;           \
        bf16* lb_ = &BUF[(w * 8) * DIM];                                     \
        _Pragma("unroll") for (int q_ = 0; q_ < 4; ++q_) {                   \
            GLOAD_LDS(tb_ + (q_ * 2) * DIM + vo[q_],                         \
                      lb_ + (q_ * 2) * DIM);                                 \
        }                                                                    \
    } while (0)

#define FLUSH_ROWS                                                           \
    do {                                                                     \
        float tr_;                                                           \
        TREE16(s0, tr_);                                                     \
        const int r_ = (lo >> 1) & 15;                                       \
        const int rowoff_ = (r_ & 3) + 8 * (r_ >> 2) + 4 * hi;               \
        if ((l & 1) == 0)                                                    \
            atomicAdd(&Tg[it * 128 + w * 32 + rowoff_], tr_);                \
    } while (0)

    int t = 0, jcn, itn;
    bool has_next;

#define NEXT_DECODE                                                          \
    do {                                                                     \
        has_next = (t + 1 < nrem);                                           \
        if (has_next) {                                                      \
            jcn = jc + 1; itn = it;                                          \
            if (jcn == NJC) { itn = it + 1; jcn = 4 * itn; }                 \
        } else { jcn = jc; itn = it; }                                       \
    } while (0)

    // WN = steady wait (next issued), WL = last-tile wait (no next issued)
#define TILE_BODY(BR, BW, WN, WL)                                            \
    do {                                                                     \
        asm volatile("s_barrier" ::: "memory");                              \
        if (has_next) {                                                      \
            ISSUE(jcn, BW);                                                  \
            asm volatile("s_waitcnt vmcnt(" #WN ")" ::: "memory");           \
        } else {                                                             \
            asm volatile("s_waitcnt vmcnt(" #WL ")" ::: "memory");           \
        }                                                                    \
        asm volatile("s_barrier" ::: "memory");                              \
        f32x16 c0;                                                           \
        _Pragma("unroll") for (int r_ = 0; r_ < 16; ++r_) c0[r_] = 0.f;      \
        __builtin_amdgcn_s_setprio(1);                                       \
        _Pragma("unroll") for (int k_ = 0; k_ < 16; ++k_) {                  \
            const int cc_ = k_ * 2 + hi;                                     \
            const int slot_ = (cc_ & 24) | ((cc_ & 7) ^ mx7);                \
            bf16x8 b_ = *(const bf16x8*)&BR[rbase + slot_ * 8];              \
            c0 = __builtin_amdgcn_mfma_f32_32x32x16_bf16(af[k_], b_, c0, 0, 0, 0); \
        }                                                                    \
        __builtin_amdgcn_s_setprio(0);                                       \
        float cs_ = 0.f;                                                     \
        _Pragma("unroll") for (int r_ = 0; r_ < 16; ++r_) {                  \
            float e_ = __builtin_amdgcn_exp2f(c0[r_]);                       \
            s0[r_] += e_;                                                    \
            cs_ += e_;                                                       \
        }                                                                    \
        cs_ += __shfl_xor(cs_, 32);                                          \
        /* col-sum flush: UNCONDITIONAL instr (uniform vmcnt queue); adds  */ \
        /* 0.0 on the diagonal 128x128 block (covered by row sums).        */ \
        const float fv_ = ((jc >> 2) == it) ? 0.0f : cs_;                    \
        if (hi == 0) atomicAdd(&Tg[jc * 32 + lo], fv_);                      \
    } while (0)

    // advance to next tile; at it-segment boundary: flush row sums, reload af
#define ADVANCE                                                              \
    do {                                                                     \
        ++t;                                                                 \
        if (itn != it) {                                                     \
            FLUSH_ROWS;                                                      \
            it = itn;                                                        \
            LOAD_AF;                                                         \
            _Pragma("unroll") for (int r_ = 0; r_ < 16; ++r_) s0[r_] = 0.f;  \
        }                                                                    \
        jc = jcn;                                                            \
    } while (0)

    ISSUE(jc, Bs0);
    // peeled first tile: no atomic in the queue yet -> vmcnt(4)/(0)
    NEXT_DECODE;
    TILE_BODY(Bs0, Bs1, 4, 0);
    ADVANCE;
    while (t < nrem) {
        NEXT_DECODE;
        TILE_BODY(Bs1, Bs0, 5, 1);
        ADVANCE;
        if (t >= nrem) break;
        NEXT_DECODE;
        TILE_BODY(Bs0, Bs1, 5, 1);
        ADVANCE;
    }
    FLUSH_ROWS;

#undef ISSUE
#undef TILE_BODY
#undef NEXT_DECODE
#undef ADVANCE
#undef FLUSH_ROWS
#undef LOAD_AF
}

// Kernel 3: loss_i = ln2*(log2(T'_i) - s2'_i), mean over rows.
__global__ void __launch_bounds__(256) final_kernel(const float* __restrict__ Tg,
                                                    const float* __restrict__ Dg,
                                                    float* __restrict__ out) {
    __shared__ float red[4];
    const int i = blockIdx.x * 256 + threadIdx.x;
    float c = LN2F * (__log2f(Tg[i]) - Dg[i]) * (1.0f / (float)N_ROWS);
#pragma unroll
    for (int m = 1; m < 64; m <<= 1) c += __shfl_xor(c, m, 64);
    if ((threadIdx.x & 63) == 0) red[threadIdx.x >> 6] = c;
    __syncthreads();
    if (threadIdx.x == 0)
        atomicAdd(out, red[0] + red[1] + red[2] + red[3]);
}

extern "C" void kernel_launch(void* const* d_in, const int* in_sizes, int n_in,
                              void* d_out, int out_size, void* d_ws, size_t ws_size,
                              hipStream_t stream) {
    const float* emb = (const float*)d_in[0];
    float* out = (float*)d_out;
    bf16* Abf = (bf16*)d_ws;
    float* Tg = (float*)((char*)d_ws + WS_T_OFF);
    float* Dg = (float*)((char*)d_ws + WS_D_OFF);

    hipLaunchKernelGGL(normalize_kernel, dim3(N_ROWS / 4), dim3(256), 0, stream,
                       emb, Abf, Tg, Dg, out);
    hipLaunchKernelGGL(loss_kernel, dim3(NBLKS), dim3(256), 0, stream,
                       Abf, Tg);
    hipLaunchKernelGGL(final_kernel, dim3(N_ROWS / 256), dim3(256), 0, stream,
                       Tg, Dg, out);
}